// Round 4
// baseline (330.496 us; speedup 1.0000x reference)
//
#include <hip/hip_runtime.h>

// SelfAttentionHead R4: occupancy round.
//  qkv      : 32-row M-tiles -> 1024 blocks (4 blocks/CU, 4 waves/SIMD),
//             register-prefetch pipeline across the two barriers.
//  attn_part: split-s flash chunks (512 cols = 8 kt-tiles per wave),
//             8192 single-wave blocks (~5 waves/SIMD demand), partials to ws.
//  attn_red : exact flash merge of <=4 partials per 16-row q-strip.
// Transposed-MFMA trick from R3 kept: S^T = K*Q^T, O^T = V^T*P^T
// (A/B lane maps identical => operand swap transposes the product).

typedef __bf16 bf16x8 __attribute__((ext_vector_type(8)));
typedef __bf16 bf16x4 __attribute__((ext_vector_type(4)));
typedef float f32x4 __attribute__((ext_vector_type(4)));

constexpr int kE = 1024;
constexpr int kH = 64;
constexpr int kT = 2048;
constexpr int kB = 16;
constexpr int kM = kB * kT;
constexpr float kQScale = 0.125f * 1.44269504088896340736f;  // H^-0.5 * log2(e)

#define MFMA16(a, b, c) __builtin_amdgcn_mfma_f32_16x16x32_bf16((a), (b), (c), 0, 0, 0)

// ---------------------------------------------------------------- prep_w
__global__ __launch_bounds__(256)
void prep_w(const float* __restrict__ Wq, const float* __restrict__ Wk,
            const float* __restrict__ Wv, __bf16* __restrict__ WbT)
{
    __shared__ float tl[64][65];
    const int mat = blockIdx.x >> 4;
    const int k0 = (blockIdx.x & 15) * 64;
    const float* src = (mat == 0) ? Wq : (mat == 1) ? Wk : Wv;

    const int t = threadIdx.x;
    const int kr = t >> 2;
    const int cg = (t & 3) * 16;
    #pragma unroll
    for (int i = 0; i < 4; ++i) {
        float4 v = *(const float4*)&src[(size_t)(k0 + kr) * kH + cg + 4 * i];
        tl[cg + 4 * i + 0][kr] = v.x;
        tl[cg + 4 * i + 1][kr] = v.y;
        tl[cg + 4 * i + 2][kr] = v.z;
        tl[cg + 4 * i + 3][kr] = v.w;
    }
    __syncthreads();
    const int nl = t >> 2;
    const int kg = (t & 3) * 16;
    bf16x8 o0, o1;
    #pragma unroll
    for (int j = 0; j < 8; ++j) {
        o0[j] = (__bf16)tl[nl][kg + j];
        o1[j] = (__bf16)tl[nl][kg + 8 + j];
    }
    *(bf16x8*)&WbT[(size_t)(mat * 64 + nl) * kE + k0 + kg] = o0;
    *(bf16x8*)&WbT[(size_t)(mat * 64 + nl) * kE + k0 + kg + 8] = o1;
}

// ---------------------------------------------------------------- qkv
// 1024 blocks, 256 threads (4 waves). Block: 32 rows x 192 cols (q|k|v).
// Wave w: n-tiles 3w..3w+2, m-tiles 0..1. Register-prefetch pipeline.
__global__ __launch_bounds__(256)
void qkv(const float* __restrict__ x, const __bf16* __restrict__ WbT,
         __bf16* __restrict__ qo, __bf16* __restrict__ ko, __bf16* __restrict__ vT)
{
    __shared__ __align__(16) __bf16 As[32][72];
    __shared__ __align__(16) __bf16 Bs[192][72];

    const int t = threadIdx.x;
    const int lane = t & 63;
    const int w = t >> 6;
    const int l15 = lane & 15;
    const int q = lane >> 4;
    const int row0 = blockIdx.x * 32;

    f32x4 acc[2][3];
    #pragma unroll
    for (int mt = 0; mt < 2; ++mt)
        #pragma unroll
        for (int nt = 0; nt < 3; ++nt) acc[mt][nt] = (f32x4){0.f, 0.f, 0.f, 0.f};

    // staging indices: A row ar, 8 floats at ac; B 6 chunks/thread
    const int ar = t >> 3;
    const int ac = (t & 7) * 8;

    float4 a0, a1;
    bf16x8 breg[6];
    {
        const float* ap = &x[(size_t)(row0 + ar) * kE + ac];
        a0 = *(const float4*)ap;
        a1 = *(const float4*)(ap + 4);
        #pragma unroll
        for (int j = 0; j < 6; ++j) {
            int id = t + 256 * j;
            breg[j] = *(const bf16x8*)&WbT[(size_t)(id >> 3) * kE + (id & 7) * 8];
        }
    }

    for (int k0 = 0; k0 < kE; k0 += 64) {
        // write staged regs to LDS
        bf16x8 ab;
        ab[0] = (__bf16)a0.x; ab[1] = (__bf16)a0.y; ab[2] = (__bf16)a0.z; ab[3] = (__bf16)a0.w;
        ab[4] = (__bf16)a1.x; ab[5] = (__bf16)a1.y; ab[6] = (__bf16)a1.z; ab[7] = (__bf16)a1.w;
        *(bf16x8*)&As[ar][ac] = ab;
        #pragma unroll
        for (int j = 0; j < 6; ++j) {
            int id = t + 256 * j;
            *(bf16x8*)&Bs[id >> 3][(id & 7) * 8] = breg[j];
        }
        __syncthreads();

        // prefetch next tile's globals (in flight during MFMA below)
        if (k0 + 64 < kE) {
            const float* ap = &x[(size_t)(row0 + ar) * kE + k0 + 64 + ac];
            a0 = *(const float4*)ap;
            a1 = *(const float4*)(ap + 4);
            #pragma unroll
            for (int j = 0; j < 6; ++j) {
                int id = t + 256 * j;
                breg[j] = *(const bf16x8*)&WbT[(size_t)(id >> 3) * kE + k0 + 64 + (id & 7) * 8];
            }
        }

        #pragma unroll
        for (int ks = 0; ks < 2; ++ks) {
            bf16x8 a4[2];
            #pragma unroll
            for (int mt = 0; mt < 2; ++mt)
                a4[mt] = *(const bf16x8*)&As[mt * 16 + l15][ks * 32 + q * 8];
            #pragma unroll
            for (int nt = 0; nt < 3; ++nt) {
                bf16x8 b = *(const bf16x8*)&Bs[w * 48 + nt * 16 + l15][ks * 32 + q * 8];
                #pragma unroll
                for (int mt = 0; mt < 2; ++mt)
                    acc[mt][nt] = MFMA16(a4[mt], b, acc[mt][nt]);
            }
        }
        __syncthreads();
    }

    const int batch = row0 >> 11;
    const int tr0 = row0 & 2047;
    #pragma unroll
    for (int nt = 0; nt < 3; ++nt) {
        const int col0 = w * 48 + nt * 16;
        const int mat = col0 >> 6;
        const int c = (col0 & 63) + l15;
        if (mat == 2) {
            #pragma unroll
            for (int mt = 0; mt < 2; ++mt) {
                const int trow = tr0 + mt * 16 + q * 4;
                bf16x4 pk;
                #pragma unroll
                for (int r = 0; r < 4; ++r) pk[r] = (__bf16)acc[mt][nt][r];
                *(bf16x4*)&vT[((size_t)batch * kH + c) * kT + trow] = pk;
            }
        } else {
            __bf16* dst = (mat == 0) ? qo : ko;
            const float sc_ = (mat == 0) ? kQScale : 1.0f;
            #pragma unroll
            for (int mt = 0; mt < 2; ++mt)
                #pragma unroll
                for (int r = 0; r < 4; ++r) {
                    const size_t row = row0 + mt * 16 + q * 4 + r;
                    dst[row * kH + c] = (__bf16)(acc[mt][nt][r] * sc_);
                }
        }
    }
}

// ---------------------------------------------------------------- attn_part
// 8192 single-wave blocks: (batch, q16, chunk). Chunk = 8 kt-tiles (512 cols).
// Lane l15 owns q-row q16*16+l15. Writes unnormalized O^T partial + (m,l).
__global__ __launch_bounds__(64, 4)
void attn_part(const __bf16* __restrict__ qm, const __bf16* __restrict__ km,
               const __bf16* __restrict__ vT, float* __restrict__ pO,
               float* __restrict__ pml)
{
    __shared__ __align__(16) __bf16 Ps[16][72];

    const int lane = threadIdx.x;
    const int l15 = lane & 15;
    const int Q = lane >> 4;

    const int bid = blockIdx.x;
    const int c = bid & 3;
    const int q16 = 127 - ((bid >> 2) & 127);   // long strips first
    const int batch = bid >> 9;
    const int last = q16 >> 2;
    const int nch = (last + 8) >> 3;            // ceil((last+1)/8)
    if (c >= nch) return;
    const int kt0 = c * 8;
    const int kt1 = min(kt0 + 8, last + 1);
    const int qrow = q16 * 16 + l15;

    const __bf16* qb = qm + (size_t)batch * kT * kH;
    const __bf16* kb = km + (size_t)batch * kT * kH;
    const __bf16* vb = vT + (size_t)batch * kH * kT;

    bf16x8 aq[2];
    aq[0] = *(const bf16x8*)&qb[(size_t)qrow * kH + Q * 8];
    aq[1] = *(const bf16x8*)&qb[(size_t)qrow * kH + 32 + Q * 8];

    f32x4 O[4];
    #pragma unroll
    for (int i = 0; i < 4; ++i) O[i] = (f32x4){0.f, 0.f, 0.f, 0.f};
    float m_ = -3.0e38f, l_ = 0.f;

    for (int kt = kt0; kt < kt1; ++kt) {
        const int s0 = kt * 64;
        bf16x8 kf[8], vf[8];
        #pragma unroll
        for (int ks = 0; ks < 2; ++ks)
            #pragma unroll
            for (int nt = 0; nt < 4; ++nt)
                kf[ks * 4 + nt] =
                    *(const bf16x8*)&kb[(size_t)(s0 + nt * 16 + l15) * kH + ks * 32 + Q * 8];
        #pragma unroll
        for (int ht = 0; ht < 4; ++ht)
            #pragma unroll
            for (int ss = 0; ss < 2; ++ss)
                vf[ht * 2 + ss] =
                    *(const bf16x8*)&vb[(size_t)(ht * 16 + l15) * kT + s0 + ss * 32 + Q * 8];

        // S^T = K * Q^T
        f32x4 sacc[4];
        #pragma unroll
        for (int nt = 0; nt < 4; ++nt) sacc[nt] = (f32x4){0.f, 0.f, 0.f, 0.f};
        #pragma unroll
        for (int ks = 0; ks < 2; ++ks)
            #pragma unroll
            for (int nt = 0; nt < 4; ++nt)
                sacc[nt] = MFMA16(kf[ks * 4 + nt], aq[ks], sacc[nt]);

        if (kt == last) {   // only the diagonal tile needs masking
            #pragma unroll
            for (int nt = 0; nt < 4; ++nt)
                #pragma unroll
                for (int r = 0; r < 4; ++r)
                    if (s0 + nt * 16 + Q * 4 + r > qrow) sacc[nt][r] = -3.0e38f;
        }

        // online softmax: register reduce + 2 shuffles
        float mx = sacc[0][0];
        #pragma unroll
        for (int nt = 0; nt < 4; ++nt)
            #pragma unroll
            for (int r = 0; r < 4; ++r) mx = fmaxf(mx, sacc[nt][r]);
        mx = fmaxf(mx, __shfl_xor(mx, 16));
        mx = fmaxf(mx, __shfl_xor(mx, 32));
        const float mnew = fmaxf(m_, mx);
        const float alpha = __builtin_amdgcn_exp2f(m_ - mnew);
        float rs = 0.f;
        #pragma unroll
        for (int nt = 0; nt < 4; ++nt)
            #pragma unroll
            for (int r = 0; r < 4; ++r) {
                const float p = __builtin_amdgcn_exp2f(sacc[nt][r] - mnew);
                sacc[nt][r] = p;
                rs += p;
            }
        rs += __shfl_xor(rs, 16);
        rs += __shfl_xor(rs, 32);
        l_ = l_ * alpha + rs;
        m_ = mnew;
        #pragma unroll
        for (int ht = 0; ht < 4; ++ht) O[ht] *= alpha;

        // P^T round-trip through wave-private LDS strip
        #pragma unroll
        for (int nt = 0; nt < 4; ++nt) {
            bf16x4 pk;
            #pragma unroll
            for (int r = 0; r < 4; ++r) pk[r] = (__bf16)sacc[nt][r];
            *(bf16x4*)&Ps[l15][nt * 16 + Q * 4] = pk;
        }
        bf16x8 pb0 = *(const bf16x8*)&Ps[l15][Q * 8];
        bf16x8 pb1 = *(const bf16x8*)&Ps[l15][32 + Q * 8];

        #pragma unroll
        for (int ht = 0; ht < 4; ++ht) {
            O[ht] = MFMA16(vf[ht * 2 + 0], pb0, O[ht]);
            O[ht] = MFMA16(vf[ht * 2 + 1], pb1, O[ht]);
        }
    }

    // partials: lane-contiguous 64 B per lane; (m,l) once per q-row
    const int task = (batch * 128 + q16) * 4 + c;
    float* po = pO + ((size_t)task * 64 + lane) * 16;
    #pragma unroll
    for (int ht = 0; ht < 4; ++ht) {
        float4 o4;
        o4.x = O[ht][0]; o4.y = O[ht][1]; o4.z = O[ht][2]; o4.w = O[ht][3];
        *(float4*)&po[ht * 4] = o4;
    }
    if (Q == 0) {
        pml[task * 32 + l15 * 2] = m_;
        pml[task * 32 + l15 * 2 + 1] = l_;
    }
}

// ---------------------------------------------------------------- attn_red
// 2048 blocks x 64 thr: one per (batch, q16). Exact flash merge of <=4 partials.
__global__ __launch_bounds__(64)
void attn_red(const float* __restrict__ pO, const float* __restrict__ pml,
              float* __restrict__ out)
{
    const int lane = threadIdx.x;
    const int l15 = lane & 15;
    const int Q = lane >> 4;
    const int q16 = blockIdx.x & 127;
    const int batch = blockIdx.x >> 7;
    const int nch = ((q16 >> 2) + 8) >> 3;
    const int base = (batch * 128 + q16) * 4;

    float M = -3.0e38f;
    for (int c = 0; c < nch; ++c)
        M = fmaxf(M, pml[(base + c) * 32 + l15 * 2]);

    float L = 0.f;
    f32x4 O[4];
    #pragma unroll
    for (int i = 0; i < 4; ++i) O[i] = (f32x4){0.f, 0.f, 0.f, 0.f};

    for (int c = 0; c < nch; ++c) {
        const float mc = pml[(base + c) * 32 + l15 * 2];
        const float lc = pml[(base + c) * 32 + l15 * 2 + 1];
        const float sc = __builtin_amdgcn_exp2f(mc - M);
        L += sc * lc;
        const float* po = pO + ((size_t)(base + c) * 64 + lane) * 16;
        #pragma unroll
        for (int ht = 0; ht < 4; ++ht) {
            float4 o4 = *(const float4*)&po[ht * 4];
            O[ht][0] += sc * o4.x; O[ht][1] += sc * o4.y;
            O[ht][2] += sc * o4.z; O[ht][3] += sc * o4.w;
        }
    }

    const float inv = 1.0f / L;
    float* orow = out + ((size_t)batch * kT + q16 * 16 + l15) * kH;
    #pragma unroll
    for (int ht = 0; ht < 4; ++ht) {
        float4 o4;
        o4.x = O[ht][0] * inv; o4.y = O[ht][1] * inv;
        o4.z = O[ht][2] * inv; o4.w = O[ht][3] * inv;
        *(float4*)&orow[ht * 16 + Q * 4] = o4;
    }
}

extern "C" void kernel_launch(void* const* d_in, const int* in_sizes, int n_in,
                              void* d_out, int out_size, void* d_ws, size_t ws_size,
                              hipStream_t stream)
{
    (void)in_sizes; (void)n_in; (void)out_size; (void)ws_size;
    const float* x  = (const float*)d_in[0];
    const float* Wk = (const float*)d_in[1];
    const float* Wq = (const float*)d_in[2];
    const float* Wv = (const float*)d_in[3];

    __bf16* WbT = (__bf16*)d_ws;                        // 384 KiB
    __bf16* qb   = WbT + (size_t)192 * kE;              // 4 MiB each
    __bf16* kbuf = qb + (size_t)kM * kH;
    __bf16* vT   = kbuf + (size_t)kM * kH;
    float*  pO   = (float*)(vT + (size_t)kM * kH);      // 8192*64*16 f32 = 32 MiB
    float*  pml  = pO + (size_t)8192 * 64 * 16;         // 8192*32 f32 = 1 MiB

    prep_w<<<48, 256, 0, stream>>>(Wq, Wk, Wv, WbT);
    qkv<<<kM / 32, 256, 0, stream>>>(x, WbT, qb, kbuf, vT);
    attn_part<<<16 * 128 * 4, 64, 0, stream>>>(qb, kbuf, vT, pO, pml);
    attn_red<<<16 * 128, 64, 0, stream>>>(pO, pml, (float*)d_out);
}

// Round 5
// 285.200 us; speedup vs baseline: 1.1588x; 1.1588x over previous
//
#include <hip/hip_runtime.h>

// SelfAttentionHead R5:
//  qkv : NO LDS, NO barriers. A/B MFMA fragments loaded directly from global
//        (x rows L1-cached; WbT L2-resident). 64-row x 192-col blocks, 24 MFMA/iter.
//  attn: 4-wave/64-q-row blocks. K and V^T staged coalesced into LDS (R2-style),
//        transposed-MFMA register softmax (R3-style: S^T = K*Q^T so each lane
//        owns a q-row), register prefetch of next tile across the barrier.
// Fragment maps (verified R2-R4): A[m=l15][k=Q*8+j] == B[k=Q*8+j][n=l15];
// C/D: col=l15, row=Q*4+reg. Operand swap == transposed product.

typedef __bf16 bf16x8 __attribute__((ext_vector_type(8)));
typedef __bf16 bf16x4 __attribute__((ext_vector_type(4)));
typedef float f32x4 __attribute__((ext_vector_type(4)));

constexpr int kE = 1024;
constexpr int kH = 64;
constexpr int kT = 2048;
constexpr int kB = 16;
constexpr int kM = kB * kT;
constexpr float kQScale = 0.125f * 1.44269504088896340736f;  // H^-0.5 * log2(e)

#define MFMA16(a, b, c) __builtin_amdgcn_mfma_f32_16x16x32_bf16((a), (b), (c), 0, 0, 0)

// ---------------------------------------------------------------- prep_w
__global__ __launch_bounds__(256)
void prep_w(const float* __restrict__ Wq, const float* __restrict__ Wk,
            const float* __restrict__ Wv, __bf16* __restrict__ WbT)
{
    __shared__ float tl[64][65];
    const int mat = blockIdx.x >> 4;
    const int k0 = (blockIdx.x & 15) * 64;
    const float* src = (mat == 0) ? Wq : (mat == 1) ? Wk : Wv;

    const int t = threadIdx.x;
    const int kr = t >> 2;
    const int cg = (t & 3) * 16;
    #pragma unroll
    for (int i = 0; i < 4; ++i) {
        float4 v = *(const float4*)&src[(size_t)(k0 + kr) * kH + cg + 4 * i];
        tl[cg + 4 * i + 0][kr] = v.x;
        tl[cg + 4 * i + 1][kr] = v.y;
        tl[cg + 4 * i + 2][kr] = v.z;
        tl[cg + 4 * i + 3][kr] = v.w;
    }
    __syncthreads();
    const int nl = t >> 2;
    const int kg = (t & 3) * 16;
    bf16x8 o0, o1;
    #pragma unroll
    for (int j = 0; j < 8; ++j) {
        o0[j] = (__bf16)tl[nl][kg + j];
        o1[j] = (__bf16)tl[nl][kg + 8 + j];
    }
    *(bf16x8*)&WbT[(size_t)(mat * 64 + nl) * kE + k0 + kg] = o0;
    *(bf16x8*)&WbT[(size_t)(mat * 64 + nl) * kE + k0 + kg + 8] = o1;
}

// ---------------------------------------------------------------- qkv
// 512 blocks, 256 threads (4 waves). Block: 64 rows x 192 cols (q|k|v).
// Wave w: n-tiles 3w..3w+2, m-tiles 0..3. Zero LDS, zero barriers.
__global__ __launch_bounds__(256)
void qkv(const float* __restrict__ x, const __bf16* __restrict__ WbT,
         __bf16* __restrict__ qo, __bf16* __restrict__ ko, __bf16* __restrict__ vT)
{
    const int t = threadIdx.x;
    const int lane = t & 63;
    const int w = t >> 6;
    const int l15 = lane & 15;
    const int q = lane >> 4;
    const int row0 = blockIdx.x * 64;

    f32x4 acc[4][3];
    #pragma unroll
    for (int mt = 0; mt < 4; ++mt)
        #pragma unroll
        for (int nt = 0; nt < 3; ++nt) acc[mt][nt] = (f32x4){0.f, 0.f, 0.f, 0.f};

    // per-lane base pointers (row fixed by l15, k walks)
    const float* xrow[4];
    #pragma unroll
    for (int mt = 0; mt < 4; ++mt)
        xrow[mt] = &x[(size_t)(row0 + mt * 16 + l15) * kE + q * 8];
    const __bf16* brow[3];
    #pragma unroll
    for (int nt = 0; nt < 3; ++nt)
        brow[nt] = &WbT[(size_t)(w * 48 + nt * 16 + l15) * kE + q * 8];

    #pragma unroll 2
    for (int k0 = 0; k0 < kE; k0 += 64) {
        bf16x8 bfrag[2][3];
        #pragma unroll
        for (int ks = 0; ks < 2; ++ks)
            #pragma unroll
            for (int nt = 0; nt < 3; ++nt)
                bfrag[ks][nt] = *(const bf16x8*)&brow[nt][k0 + ks * 32];

        bf16x8 afrag[2][4];
        #pragma unroll
        for (int mt = 0; mt < 4; ++mt)
            #pragma unroll
            for (int ks = 0; ks < 2; ++ks) {
                float4 u0 = *(const float4*)&xrow[mt][k0 + ks * 32];
                float4 u1 = *(const float4*)&xrow[mt][k0 + ks * 32 + 4];
                bf16x8 a;
                a[0] = (__bf16)u0.x; a[1] = (__bf16)u0.y;
                a[2] = (__bf16)u0.z; a[3] = (__bf16)u0.w;
                a[4] = (__bf16)u1.x; a[5] = (__bf16)u1.y;
                a[6] = (__bf16)u1.z; a[7] = (__bf16)u1.w;
                afrag[ks][mt] = a;
            }

        #pragma unroll
        for (int ks = 0; ks < 2; ++ks)
            #pragma unroll
            for (int nt = 0; nt < 3; ++nt)
                #pragma unroll
                for (int mt = 0; mt < 4; ++mt)
                    acc[mt][nt] = MFMA16(afrag[ks][mt], bfrag[ks][nt], acc[mt][nt]);
    }

    const int batch = row0 >> 11;
    const int tr0 = row0 & 2047;
    #pragma unroll
    for (int nt = 0; nt < 3; ++nt) {
        const int col0 = w * 48 + nt * 16;
        const int mat = col0 >> 6;
        const int c = (col0 & 63) + l15;
        if (mat == 2) {
            #pragma unroll
            for (int mt = 0; mt < 4; ++mt) {
                const int trow = tr0 + mt * 16 + q * 4;
                bf16x4 pk;
                #pragma unroll
                for (int r = 0; r < 4; ++r) pk[r] = (__bf16)acc[mt][nt][r];
                *(bf16x4*)&vT[((size_t)batch * kH + c) * kT + trow] = pk;
            }
        } else {
            __bf16* dst = (mat == 0) ? qo : ko;
            const float sc_ = (mat == 0) ? kQScale : 1.0f;
            #pragma unroll
            for (int mt = 0; mt < 4; ++mt)
                #pragma unroll
                for (int r = 0; r < 4; ++r) {
                    const size_t row = row0 + mt * 16 + q * 4 + r;
                    dst[row * kH + c] = (__bf16)(acc[mt][nt][r] * sc_);
                }
        }
    }
}

// ---------------------------------------------------------------- attn
// 512 blocks (qi descending), 256 threads (4 waves). Block: 64 q-rows;
// wave w owns rows w*16..+15 (lane l15 owns one q-row via transposed MFMA).
// K and V^T tiles staged coalesced in LDS; next tile prefetched into regs.
__global__ __launch_bounds__(256)
void attn(const __bf16* __restrict__ qm, const __bf16* __restrict__ km,
          const __bf16* __restrict__ vT, float* __restrict__ out)
{
    __shared__ __align__(16) __bf16 Ks[64][72];
    __shared__ __align__(16) __bf16 Vt[64][72];     // [h][s]
    __shared__ __align__(16) __bf16 Ps[4][16][72];  // per-wave P^T strip

    const int t = threadIdx.x;
    const int lane = t & 63;
    const int w = t >> 6;
    const int l15 = lane & 15;
    const int Q = lane >> 4;

    const int batch = blockIdx.x & 15;
    const int qi = 31 - (blockIdx.x >> 4);          // long blocks first
    const int q0 = qi * 64;
    const int qrow = q0 + w * 16 + l15;

    const __bf16* qb = qm + (size_t)batch * kT * kH;
    const __bf16* kb = km + (size_t)batch * kT * kH;
    const __bf16* vb = vT + (size_t)batch * kH * kT;

    // Q fragment (B-operand of S^T), loaded once from global
    bf16x8 aq[2];
    aq[0] = *(const bf16x8*)&qb[(size_t)qrow * kH + Q * 8];
    aq[1] = *(const bf16x8*)&qb[(size_t)qrow * kH + 32 + Q * 8];

    f32x4 O[4];
    #pragma unroll
    for (int i = 0; i < 4; ++i) O[i] = (f32x4){0.f, 0.f, 0.f, 0.f};
    float m_ = -3.0e38f, l_ = 0.f;

    // staging: thread covers row sr, cols scg..scg+15 (coalesced 32 B/thread)
    const int sr = t >> 2;
    const int scg = (t & 3) * 16;

    bf16x8 k0r, k1r, v0r, v1r;
    {
        k0r = *(const bf16x8*)&kb[(size_t)sr * kH + scg];
        k1r = *(const bf16x8*)&kb[(size_t)sr * kH + scg + 8];
        v0r = *(const bf16x8*)&vb[(size_t)sr * kT + scg];
        v1r = *(const bf16x8*)&vb[(size_t)sr * kT + scg + 8];
    }

    for (int kt = 0; kt <= qi; ++kt) {
        // stage current tile from regs
        *(bf16x8*)&Ks[sr][scg] = k0r;
        *(bf16x8*)&Ks[sr][scg + 8] = k1r;
        *(bf16x8*)&Vt[sr][scg] = v0r;
        *(bf16x8*)&Vt[sr][scg + 8] = v1r;
        __syncthreads();

        // prefetch next tile (in flight across the compute below)
        if (kt < qi) {
            const int sn = (kt + 1) * 64;
            k0r = *(const bf16x8*)&kb[(size_t)(sn + sr) * kH + scg];
            k1r = *(const bf16x8*)&kb[(size_t)(sn + sr) * kH + scg + 8];
            v0r = *(const bf16x8*)&vb[(size_t)sr * kT + sn + scg];
            v1r = *(const bf16x8*)&vb[(size_t)sr * kT + sn + scg + 8];
        }

        // fragments from LDS (b128, <=2-way conflicts)
        bf16x8 kf[8], vf[8];
        #pragma unroll
        for (int ks = 0; ks < 2; ++ks)
            #pragma unroll
            for (int nt = 0; nt < 4; ++nt)
                kf[ks * 4 + nt] = *(const bf16x8*)&Ks[nt * 16 + l15][ks * 32 + Q * 8];
        #pragma unroll
        for (int ht = 0; ht < 4; ++ht)
            #pragma unroll
            for (int ss = 0; ss < 2; ++ss)
                vf[ht * 2 + ss] = *(const bf16x8*)&Vt[ht * 16 + l15][ss * 32 + Q * 8];

        // S^T = K * Q^T (lane owns q-col l15)
        f32x4 sacc[4];
        #pragma unroll
        for (int nt = 0; nt < 4; ++nt) sacc[nt] = (f32x4){0.f, 0.f, 0.f, 0.f};
        #pragma unroll
        for (int ks = 0; ks < 2; ++ks)
            #pragma unroll
            for (int nt = 0; nt < 4; ++nt)
                sacc[nt] = MFMA16(kf[ks * 4 + nt], aq[ks], sacc[nt]);

        if (kt == qi) {   // diagonal super-tile: mask s > qrow
            const int s0 = kt * 64;
            #pragma unroll
            for (int nt = 0; nt < 4; ++nt)
                #pragma unroll
                for (int r = 0; r < 4; ++r)
                    if (s0 + nt * 16 + Q * 4 + r > qrow) sacc[nt][r] = -3.0e38f;
        }

        // online softmax: register reduce + 2 shuffles
        float mx = sacc[0][0];
        #pragma unroll
        for (int nt = 0; nt < 4; ++nt)
            #pragma unroll
            for (int r = 0; r < 4; ++r) mx = fmaxf(mx, sacc[nt][r]);
        mx = fmaxf(mx, __shfl_xor(mx, 16));
        mx = fmaxf(mx, __shfl_xor(mx, 32));
        const float mnew = fmaxf(m_, mx);
        const float alpha = __builtin_amdgcn_exp2f(m_ - mnew);
        float rs = 0.f;
        #pragma unroll
        for (int nt = 0; nt < 4; ++nt)
            #pragma unroll
            for (int r = 0; r < 4; ++r) {
                const float p = __builtin_amdgcn_exp2f(sacc[nt][r] - mnew);
                sacc[nt][r] = p;
                rs += p;
            }
        rs += __shfl_xor(rs, 16);
        rs += __shfl_xor(rs, 32);
        l_ = l_ * alpha + rs;
        m_ = mnew;
        #pragma unroll
        for (int ht = 0; ht < 4; ++ht) O[ht] *= alpha;

        // P^T round-trip through wave-private strip (packed b64 write, b128 read)
        #pragma unroll
        for (int nt = 0; nt < 4; ++nt) {
            bf16x4 pk;
            #pragma unroll
            for (int r = 0; r < 4; ++r) pk[r] = (__bf16)sacc[nt][r];
            *(bf16x4*)&Ps[w][l15][nt * 16 + Q * 4] = pk;
        }
        bf16x8 pb0 = *(const bf16x8*)&Ps[w][l15][Q * 8];
        bf16x8 pb1 = *(const bf16x8*)&Ps[w][l15][32 + Q * 8];

        // O^T += V^T * P^T
        #pragma unroll
        for (int ht = 0; ht < 4; ++ht) {
            O[ht] = MFMA16(vf[ht * 2 + 0], pb0, O[ht]);
            O[ht] = MFMA16(vf[ht * 2 + 1], pb1, O[ht]);
        }
        __syncthreads();   // protect Ks/Vt before next stage
    }

    const float inv = 1.0f / l_;
    float* orow = out + ((size_t)batch * kT + qrow) * kH;
    #pragma unroll
    for (int ht = 0; ht < 4; ++ht) {
        float4 o4;
        o4.x = O[ht][0] * inv; o4.y = O[ht][1] * inv;
        o4.z = O[ht][2] * inv; o4.w = O[ht][3] * inv;
        *(float4*)&orow[ht * 16 + Q * 4] = o4;
    }
}

extern "C" void kernel_launch(void* const* d_in, const int* in_sizes, int n_in,
                              void* d_out, int out_size, void* d_ws, size_t ws_size,
                              hipStream_t stream)
{
    (void)in_sizes; (void)n_in; (void)out_size; (void)ws_size;
    const float* x  = (const float*)d_in[0];
    const float* Wk = (const float*)d_in[1];
    const float* Wq = (const float*)d_in[2];
    const float* Wv = (const float*)d_in[3];

    __bf16* WbT  = (__bf16*)d_ws;                     // 384 KiB
    __bf16* qb   = WbT + (size_t)192 * kE;            // 4 MiB each
    __bf16* kbuf = qb + (size_t)kM * kH;
    __bf16* vT   = kbuf + (size_t)kM * kH;

    prep_w<<<48, 256, 0, stream>>>(Wq, Wk, Wv, WbT);
    qkv<<<kM / 64, 256, 0, stream>>>(x, WbT, qb, kbuf, vT);
    attn<<<kB * 32, 256, 0, stream>>>(qb, kbuf, vT, (float*)d_out);
}

// Round 6
// 278.050 us; speedup vs baseline: 1.1886x; 1.0257x over previous
//
#include <hip/hip_runtime.h>

// SelfAttentionHead R6: register-MLP round.
//  qkv : no-LDS, zero-barrier (R5 structure) + explicit register ping-pong
//        double-buffer + __launch_bounds__(256,1) so the allocator does not
//        squeeze VGPRs (R4/R5 failure mode: 56/84 VGPR -> serialized loads).
//  attn: double-buffered LDS K/V, ONE barrier per iteration; global prefetch
//        for kt+1 issued before the compute of kt (full-section latency cover).
// Fragment maps (verified R2-R5): A[m=l15][k=Q*8+j] == B[k=Q*8+j][n=l15];
// C/D: col=l15, row=Q*4+reg. Operand swap == transposed product.

typedef __bf16 bf16x8 __attribute__((ext_vector_type(8)));
typedef __bf16 bf16x4 __attribute__((ext_vector_type(4)));
typedef float f32x4 __attribute__((ext_vector_type(4)));

constexpr int kE = 1024;
constexpr int kH = 64;
constexpr int kT = 2048;
constexpr int kB = 16;
constexpr int kM = kB * kT;
constexpr float kQScale = 0.125f * 1.44269504088896340736f;  // H^-0.5 * log2(e)

#define MFMA16(a, b, c) __builtin_amdgcn_mfma_f32_16x16x32_bf16((a), (b), (c), 0, 0, 0)

// ---------------------------------------------------------------- prep_w
__global__ __launch_bounds__(256)
void prep_w(const float* __restrict__ Wq, const float* __restrict__ Wk,
            const float* __restrict__ Wv, __bf16* __restrict__ WbT)
{
    __shared__ float tl[64][65];
    const int mat = blockIdx.x >> 4;
    const int k0 = (blockIdx.x & 15) * 64;
    const float* src = (mat == 0) ? Wq : (mat == 1) ? Wk : Wv;

    const int t = threadIdx.x;
    const int kr = t >> 2;
    const int cg = (t & 3) * 16;
    #pragma unroll
    for (int i = 0; i < 4; ++i) {
        float4 v = *(const float4*)&src[(size_t)(k0 + kr) * kH + cg + 4 * i];
        tl[cg + 4 * i + 0][kr] = v.x;
        tl[cg + 4 * i + 1][kr] = v.y;
        tl[cg + 4 * i + 2][kr] = v.z;
        tl[cg + 4 * i + 3][kr] = v.w;
    }
    __syncthreads();
    const int nl = t >> 2;
    const int kg = (t & 3) * 16;
    bf16x8 o0, o1;
    #pragma unroll
    for (int j = 0; j < 8; ++j) {
        o0[j] = (__bf16)tl[nl][kg + j];
        o1[j] = (__bf16)tl[nl][kg + 8 + j];
    }
    *(bf16x8*)&WbT[(size_t)(mat * 64 + nl) * kE + k0 + kg] = o0;
    *(bf16x8*)&WbT[(size_t)(mat * 64 + nl) * kE + k0 + kg + 8] = o1;
}

// ---------------------------------------------------------------- qkv
// 512 blocks, 256 threads (4 waves). Block: 64 rows x 192 cols (q|k|v).
// Wave w: n-tiles 3w..3w+2, m-tiles 0..3. No LDS, no barriers.
// Explicit register double-buffer: load(k+1) in flight across compute(k).
__global__ __launch_bounds__(256, 1)
void qkv(const float* __restrict__ x, const __bf16* __restrict__ WbT,
         __bf16* __restrict__ qo, __bf16* __restrict__ ko, __bf16* __restrict__ vT)
{
    const int t = threadIdx.x;
    const int lane = t & 63;
    const int w = t >> 6;
    const int l15 = lane & 15;
    const int q = lane >> 4;
    const int row0 = blockIdx.x * 64;

    f32x4 acc[4][3];
    #pragma unroll
    for (int mt = 0; mt < 4; ++mt)
        #pragma unroll
        for (int nt = 0; nt < 3; ++nt) acc[mt][nt] = (f32x4){0.f, 0.f, 0.f, 0.f};

    const float* xrow[4];
    #pragma unroll
    for (int mt = 0; mt < 4; ++mt)
        xrow[mt] = &x[(size_t)(row0 + mt * 16 + l15) * kE + q * 8];
    const __bf16* brow[3];
    #pragma unroll
    for (int nt = 0; nt < 3; ++nt)
        brow[nt] = &WbT[(size_t)(w * 48 + nt * 16 + l15) * kE + q * 8];

    float4 A0[4][2][2], A1[4][2][2];
    bf16x8 B0[2][3], B1[2][3];

    auto load = [&](float4 (&A)[4][2][2], bf16x8 (&Bv)[2][3], int k0) {
        #pragma unroll
        for (int mt = 0; mt < 4; ++mt)
            #pragma unroll
            for (int ks = 0; ks < 2; ++ks) {
                A[mt][ks][0] = *(const float4*)&xrow[mt][k0 + ks * 32];
                A[mt][ks][1] = *(const float4*)&xrow[mt][k0 + ks * 32 + 4];
            }
        #pragma unroll
        for (int ks = 0; ks < 2; ++ks)
            #pragma unroll
            for (int nt = 0; nt < 3; ++nt)
                Bv[ks][nt] = *(const bf16x8*)&brow[nt][k0 + ks * 32];
    };
    auto compute = [&](float4 (&A)[4][2][2], bf16x8 (&Bv)[2][3]) {
        #pragma unroll
        for (int ks = 0; ks < 2; ++ks) {
            bf16x8 af[4];
            #pragma unroll
            for (int mt = 0; mt < 4; ++mt) {
                float4 u0 = A[mt][ks][0], u1 = A[mt][ks][1];
                bf16x8 a;
                a[0] = (__bf16)u0.x; a[1] = (__bf16)u0.y;
                a[2] = (__bf16)u0.z; a[3] = (__bf16)u0.w;
                a[4] = (__bf16)u1.x; a[5] = (__bf16)u1.y;
                a[6] = (__bf16)u1.z; a[7] = (__bf16)u1.w;
                af[mt] = a;
            }
            #pragma unroll
            for (int nt = 0; nt < 3; ++nt)
                #pragma unroll
                for (int mt = 0; mt < 4; ++mt)
                    acc[mt][nt] = MFMA16(af[mt], Bv[ks][nt], acc[mt][nt]);
        }
    };

    load(A0, B0, 0);
    #pragma unroll 1
    for (int k0 = 0; k0 < kE; k0 += 128) {
        if (k0 + 64 < kE) load(A1, B1, k0 + 64);
        compute(A0, B0);
        if (k0 + 128 < kE) load(A0, B0, k0 + 128);
        if (k0 + 64 < kE) compute(A1, B1);
    }

    const int batch = row0 >> 11;
    const int tr0 = row0 & 2047;
    #pragma unroll
    for (int nt = 0; nt < 3; ++nt) {
        const int col0 = w * 48 + nt * 16;
        const int mat = col0 >> 6;
        const int c = (col0 & 63) + l15;
        if (mat == 2) {
            #pragma unroll
            for (int mt = 0; mt < 4; ++mt) {
                const int trow = tr0 + mt * 16 + q * 4;
                bf16x4 pk;
                #pragma unroll
                for (int r = 0; r < 4; ++r) pk[r] = (__bf16)acc[mt][nt][r];
                *(bf16x4*)&vT[((size_t)batch * kH + c) * kT + trow] = pk;
            }
        } else {
            __bf16* dst = (mat == 0) ? qo : ko;
            const float sc_ = (mat == 0) ? kQScale : 1.0f;
            #pragma unroll
            for (int mt = 0; mt < 4; ++mt)
                #pragma unroll
                for (int r = 0; r < 4; ++r) {
                    const size_t row = row0 + mt * 16 + q * 4 + r;
                    dst[row * kH + c] = (__bf16)(acc[mt][nt][r] * sc_);
                }
        }
    }
}

// ---------------------------------------------------------------- attn
// 512 blocks (qi descending), 256 threads (4 waves). Block: 64 q-rows;
// wave w owns rows w*16..+15 (lane l15 owns one q-row via transposed MFMA).
// Double-buffered LDS K/V; ONE barrier per iteration; prefetch issued at top.
__global__ __launch_bounds__(256, 1)
void attn(const __bf16* __restrict__ qm, const __bf16* __restrict__ km,
          const __bf16* __restrict__ vT, float* __restrict__ out)
{
    __shared__ __align__(16) __bf16 Ks[2][64][72];
    __shared__ __align__(16) __bf16 Vt[2][64][72];  // [h][s]
    __shared__ __align__(16) __bf16 Ps[4][16][72];  // per-wave P^T strip

    const int t = threadIdx.x;
    const int lane = t & 63;
    const int w = t >> 6;
    const int l15 = lane & 15;
    const int Q = lane >> 4;

    const int batch = blockIdx.x & 15;
    const int qi = 31 - (blockIdx.x >> 4);          // long blocks first
    const int q0 = qi * 64;
    const int qrow = q0 + w * 16 + l15;

    const __bf16* qb = qm + (size_t)batch * kT * kH;
    const __bf16* kb = km + (size_t)batch * kT * kH;
    const __bf16* vb = vT + (size_t)batch * kH * kT;

    // Q fragment (B-operand of S^T), loaded once from global
    bf16x8 aq[2];
    aq[0] = *(const bf16x8*)&qb[(size_t)qrow * kH + Q * 8];
    aq[1] = *(const bf16x8*)&qb[(size_t)qrow * kH + 32 + Q * 8];

    f32x4 O[4];
    #pragma unroll
    for (int i = 0; i < 4; ++i) O[i] = (f32x4){0.f, 0.f, 0.f, 0.f};
    float m_ = -3.0e38f, l_ = 0.f;

    // staging: thread covers row sr, cols scg..scg+15 (coalesced 32 B/thread)
    const int sr = t >> 2;
    const int scg = (t & 3) * 16;

    bf16x8 k0r, k1r, v0r, v1r;
    // tile 0 -> LDS buffer 0
    k0r = *(const bf16x8*)&kb[(size_t)sr * kH + scg];
    k1r = *(const bf16x8*)&kb[(size_t)sr * kH + scg + 8];
    v0r = *(const bf16x8*)&vb[(size_t)sr * kT + scg];
    v1r = *(const bf16x8*)&vb[(size_t)sr * kT + scg + 8];
    *(bf16x8*)&Ks[0][sr][scg] = k0r;
    *(bf16x8*)&Ks[0][sr][scg + 8] = k1r;
    *(bf16x8*)&Vt[0][sr][scg] = v0r;
    *(bf16x8*)&Vt[0][sr][scg + 8] = v1r;
    __syncthreads();

    for (int kt = 0; kt <= qi; ++kt) {
        const int p = kt & 1;
        // prefetch kt+1 (latency covered by the whole compute section below)
        if (kt < qi) {
            const int sn = (kt + 1) * 64;
            k0r = *(const bf16x8*)&kb[(size_t)(sn + sr) * kH + scg];
            k1r = *(const bf16x8*)&kb[(size_t)(sn + sr) * kH + scg + 8];
            v0r = *(const bf16x8*)&vb[(size_t)sr * kT + sn + scg];
            v1r = *(const bf16x8*)&vb[(size_t)sr * kT + sn + scg + 8];
        }

        // fragments from LDS (b128, <=2-way conflicts)
        bf16x8 kf[8], vf[8];
        #pragma unroll
        for (int ks = 0; ks < 2; ++ks)
            #pragma unroll
            for (int nt = 0; nt < 4; ++nt)
                kf[ks * 4 + nt] = *(const bf16x8*)&Ks[p][nt * 16 + l15][ks * 32 + Q * 8];
        #pragma unroll
        for (int ht = 0; ht < 4; ++ht)
            #pragma unroll
            for (int ss = 0; ss < 2; ++ss)
                vf[ht * 2 + ss] = *(const bf16x8*)&Vt[p][ht * 16 + l15][ss * 32 + Q * 8];

        // S^T = K * Q^T (lane owns q-col l15)
        f32x4 sacc[4];
        #pragma unroll
        for (int nt = 0; nt < 4; ++nt) sacc[nt] = (f32x4){0.f, 0.f, 0.f, 0.f};
        #pragma unroll
        for (int ks = 0; ks < 2; ++ks)
            #pragma unroll
            for (int nt = 0; nt < 4; ++nt)
                sacc[nt] = MFMA16(kf[ks * 4 + nt], aq[ks], sacc[nt]);

        if (kt == qi) {   // diagonal super-tile: mask s > qrow
            const int s0 = kt * 64;
            #pragma unroll
            for (int nt = 0; nt < 4; ++nt)
                #pragma unroll
                for (int r = 0; r < 4; ++r)
                    if (s0 + nt * 16 + Q * 4 + r > qrow) sacc[nt][r] = -3.0e38f;
        }

        // online softmax: register reduce + 2 shuffles
        float mx = sacc[0][0];
        #pragma unroll
        for (int nt = 0; nt < 4; ++nt)
            #pragma unroll
            for (int r = 0; r < 4; ++r) mx = fmaxf(mx, sacc[nt][r]);
        mx = fmaxf(mx, __shfl_xor(mx, 16));
        mx = fmaxf(mx, __shfl_xor(mx, 32));
        const float mnew = fmaxf(m_, mx);
        const float alpha = __builtin_amdgcn_exp2f(m_ - mnew);
        float rs = 0.f;
        #pragma unroll
        for (int nt = 0; nt < 4; ++nt)
            #pragma unroll
            for (int r = 0; r < 4; ++r) {
                const float p_ = __builtin_amdgcn_exp2f(sacc[nt][r] - mnew);
                sacc[nt][r] = p_;
                rs += p_;
            }
        rs += __shfl_xor(rs, 16);
        rs += __shfl_xor(rs, 32);
        l_ = l_ * alpha + rs;
        m_ = mnew;
        #pragma unroll
        for (int ht = 0; ht < 4; ++ht) O[ht] *= alpha;

        // P^T round-trip through wave-private strip (packed b64 write, b128 read)
        #pragma unroll
        for (int nt = 0; nt < 4; ++nt) {
            bf16x4 pk;
            #pragma unroll
            for (int r = 0; r < 4; ++r) pk[r] = (__bf16)sacc[nt][r];
            *(bf16x4*)&Ps[w][l15][nt * 16 + Q * 4] = pk;
        }
        bf16x8 pb0 = *(const bf16x8*)&Ps[w][l15][Q * 8];
        bf16x8 pb1 = *(const bf16x8*)&Ps[w][l15][32 + Q * 8];

        // O^T += V^T * P^T
        #pragma unroll
        for (int ht = 0; ht < 4; ++ht) {
            O[ht] = MFMA16(vf[ht * 2 + 0], pb0, O[ht]);
            O[ht] = MFMA16(vf[ht * 2 + 1], pb1, O[ht]);
        }

        // stage kt+1 into the other buffer; single barrier ends the iteration
        if (kt < qi) {
            *(bf16x8*)&Ks[1 - p][sr][scg] = k0r;
            *(bf16x8*)&Ks[1 - p][sr][scg + 8] = k1r;
            *(bf16x8*)&Vt[1 - p][sr][scg] = v0r;
            *(bf16x8*)&Vt[1 - p][sr][scg + 8] = v1r;
        }
        __syncthreads();
    }

    const float inv = 1.0f / l_;
    float* orow = out + ((size_t)batch * kT + qrow) * kH;
    #pragma unroll
    for (int ht = 0; ht < 4; ++ht) {
        float4 o4;
        o4.x = O[ht][0] * inv; o4.y = O[ht][1] * inv;
        o4.z = O[ht][2] * inv; o4.w = O[ht][3] * inv;
        *(float4*)&orow[ht * 16 + Q * 4] = o4;
    }
}

extern "C" void kernel_launch(void* const* d_in, const int* in_sizes, int n_in,
                              void* d_out, int out_size, void* d_ws, size_t ws_size,
                              hipStream_t stream)
{
    (void)in_sizes; (void)n_in; (void)out_size; (void)ws_size;
    const float* x  = (const float*)d_in[0];
    const float* Wk = (const float*)d_in[1];
    const float* Wq = (const float*)d_in[2];
    const float* Wv = (const float*)d_in[3];

    __bf16* WbT  = (__bf16*)d_ws;                     // 384 KiB
    __bf16* qb   = WbT + (size_t)192 * kE;            // 4 MiB each
    __bf16* kbuf = qb + (size_t)kM * kH;
    __bf16* vT   = kbuf + (size_t)kM * kH;

    prep_w<<<48, 256, 0, stream>>>(Wq, Wk, Wv, WbT);
    qkv<<<kM / 64, 256, 0, stream>>>(x, WbT, qb, kbuf, vT);
    attn<<<kB * 32, 256, 0, stream>>>(qb, kbuf, vT, (float*)d_out);
}

// Round 7
// 259.214 us; speedup vs baseline: 1.2750x; 1.0727x over previous
//
#include <hip/hip_runtime.h>

// SelfAttentionHead R7: global_load_lds round (staging out of VGPRs).
//  qkv : m97-style async DMA staging, XOR-swizzled LDS, double-buffered,
//        one barrier/iter. Allocator has no staging registers to squeeze.
//  attn: single-wave blocks, NO barriers. K/V tiles DMA'd to wave-private
//        LDS; register fragments act as the double buffer; explicit
//        s_waitcnt vmcnt/lgkmcnt via inline asm. Batch-major dispatch for
//        per-XCD K/V L2 residency.
// Fragment maps (verified R2-R6): A[m=l15][k=Q*8+j] == B[k=Q*8+j][n=l15];
// C/D: col=l15, row=Q*4+reg. Operand swap == transposed product.
// XOR swizzle: 16B group g of row r stored at slot g^(r&15) [A, 16 groups]
// or g^(r&7) [B/K/V, 8 groups] -> frag ds_read_b128 at bank floor.

typedef __bf16 bf16x8 __attribute__((ext_vector_type(8)));
typedef __bf16 bf16x4 __attribute__((ext_vector_type(4)));
typedef float f32x4 __attribute__((ext_vector_type(4)));

constexpr int kE = 1024;
constexpr int kH = 64;
constexpr int kT = 2048;
constexpr int kB = 16;
constexpr int kM = kB * kT;
constexpr float kQScale = 0.125f * 1.44269504088896340736f;  // H^-0.5 * log2(e)

#define MFMA16(a, b, c) __builtin_amdgcn_mfma_f32_16x16x32_bf16((a), (b), (c), 0, 0, 0)

__device__ __forceinline__ void gl_lds16(const void* g, void* l) {
    __builtin_amdgcn_global_load_lds(
        (const __attribute__((address_space(1))) void*)g,
        (__attribute__((address_space(3))) void*)l, 16, 0, 0);
}

// ---------------------------------------------------------------- prep_w
__global__ __launch_bounds__(256)
void prep_w(const float* __restrict__ Wq, const float* __restrict__ Wk,
            const float* __restrict__ Wv, __bf16* __restrict__ WbT)
{
    __shared__ float tl[64][65];
    const int mat = blockIdx.x >> 4;
    const int k0 = (blockIdx.x & 15) * 64;
    const float* src = (mat == 0) ? Wq : (mat == 1) ? Wk : Wv;

    const int t = threadIdx.x;
    const int kr = t >> 2;
    const int cg = (t & 3) * 16;
    #pragma unroll
    for (int i = 0; i < 4; ++i) {
        float4 v = *(const float4*)&src[(size_t)(k0 + kr) * kH + cg + 4 * i];
        tl[cg + 4 * i + 0][kr] = v.x;
        tl[cg + 4 * i + 1][kr] = v.y;
        tl[cg + 4 * i + 2][kr] = v.z;
        tl[cg + 4 * i + 3][kr] = v.w;
    }
    __syncthreads();
    const int nl = t >> 2;
    const int kg = (t & 3) * 16;
    bf16x8 o0, o1;
    #pragma unroll
    for (int j = 0; j < 8; ++j) {
        o0[j] = (__bf16)tl[nl][kg + j];
        o1[j] = (__bf16)tl[nl][kg + 8 + j];
    }
    *(bf16x8*)&WbT[(size_t)(mat * 64 + nl) * kE + k0 + kg] = o0;
    *(bf16x8*)&WbT[(size_t)(mat * 64 + nl) * kE + k0 + kg + 8] = o1;
}

// ---------------------------------------------------------------- qkv
// 512 blocks, 256 threads (4 waves). Block: 64 rows x 192 cols (q|k|v).
// A-LDS: row r (0..63) x group g (0..15, 16B f32): byte = r*256 + (g^(r&15))*16
// B-LDS: row n (0..191) x group g (0..7, 16B bf16): byte = n*128 + (g^(n&7))*16
__global__ __launch_bounds__(256)
void qkv(const float* __restrict__ x, const __bf16* __restrict__ WbT,
         __bf16* __restrict__ qo, __bf16* __restrict__ ko, __bf16* __restrict__ vT)
{
    __shared__ __align__(16) char Ab[2][16384];
    __shared__ __align__(16) char Bb[2][24576];

    const int t = threadIdx.x;
    const int lane = t & 63;
    const int w = t >> 6;
    const int l15 = lane & 15;
    const int Q = lane >> 4;
    const int row0 = blockIdx.x * 64;

    f32x4 acc[4][3];
    #pragma unroll
    for (int mt = 0; mt < 4; ++mt)
        #pragma unroll
        for (int nt = 0; nt < 3; ++nt) acc[mt][nt] = (f32x4){0.f, 0.f, 0.f, 0.f};

    // DMA staging: per wave, A = 4 KB (4 instrs), B = 6 KB (6 instrs).
    // LDS dst = uniform base + lane*16 (HW). Data swizzled via global source.
    auto stage = [&](int p, int k0) {
        #pragma unroll
        for (int i = 0; i < 4; ++i) {
            const int row = (w * 4 + i) * 4 + (lane >> 4);          // linear row
            const int g = (lane & 15) ^ (i * 4 + (lane >> 4));      // slot^ (row&15)
            gl_lds16(&x[(size_t)(row0 + row) * kE + k0 + g * 4],
                     &Ab[p][(w * 4 + i) * 1024]);
        }
        #pragma unroll
        for (int i = 0; i < 6; ++i) {
            const int n = (w * 6 + i) * 8 + (lane >> 3);
            const int g = (lane & 7) ^ (lane >> 3);                 // slot ^ (n&7)
            gl_lds16(&WbT[(size_t)n * kE + k0 + g * 8],
                     &Bb[p][(w * 6 + i) * 1024]);
        }
    };

    stage(0, 0);
    __syncthreads();                       // vmcnt drain: chunk 0 landed

    for (int c = 0; c < 16; ++c) {
        const int p = c & 1;
        if (c < 15) stage(1 - p, (c + 1) * 64);   // async prefetch

        #pragma unroll
        for (int ks = 0; ks < 2; ++ks) {
            bf16x8 a4[4];
            #pragma unroll
            for (int mt = 0; mt < 4; ++mt) {
                const int row = mt * 16 + l15;
                float4 u0 = *(const float4*)&Ab[p][row * 256 + ((ks * 8 + Q * 2 + 0) ^ l15) * 16];
                float4 u1 = *(const float4*)&Ab[p][row * 256 + ((ks * 8 + Q * 2 + 1) ^ l15) * 16];
                bf16x8 a;
                a[0] = (__bf16)u0.x; a[1] = (__bf16)u0.y;
                a[2] = (__bf16)u0.z; a[3] = (__bf16)u0.w;
                a[4] = (__bf16)u1.x; a[5] = (__bf16)u1.y;
                a[6] = (__bf16)u1.z; a[7] = (__bf16)u1.w;
                a4[mt] = a;
            }
            #pragma unroll
            for (int nt = 0; nt < 3; ++nt) {
                const int n = w * 48 + nt * 16 + l15;
                bf16x8 b = *(const bf16x8*)&Bb[p][n * 128 + (((ks * 4 + Q) ^ (l15 & 7)) * 16)];
                #pragma unroll
                for (int mt = 0; mt < 4; ++mt)
                    acc[mt][nt] = MFMA16(a4[mt], b, acc[mt][nt]);
            }
        }
        __syncthreads();   // drains vmcnt (prefetch landed) + lgkm (buf p free)
    }

    const int batch = row0 >> 11;
    const int tr0 = row0 & 2047;
    #pragma unroll
    for (int nt = 0; nt < 3; ++nt) {
        const int col0 = w * 48 + nt * 16;
        const int mat = col0 >> 6;
        const int c = (col0 & 63) + l15;
        if (mat == 2) {
            #pragma unroll
            for (int mt = 0; mt < 4; ++mt) {
                const int trow = tr0 + mt * 16 + Q * 4;
                bf16x4 pk;
                #pragma unroll
                for (int r = 0; r < 4; ++r) pk[r] = (__bf16)acc[mt][nt][r];
                *(bf16x4*)&vT[((size_t)batch * kH + c) * kT + trow] = pk;
            }
        } else {
            __bf16* dst = (mat == 0) ? qo : ko;
            const float sc_ = (mat == 0) ? kQScale : 1.0f;
            #pragma unroll
            for (int mt = 0; mt < 4; ++mt)
                #pragma unroll
                for (int r = 0; r < 4; ++r) {
                    const size_t row = row0 + mt * 16 + Q * 4 + r;
                    dst[row * kH + c] = (__bf16)(acc[mt][nt][r] * sc_);
                }
        }
    }
}

// ---------------------------------------------------------------- attn
// 2048 single-wave blocks, batch-major (L2 locality), long strips first
// within a batch. Lane l15 owns q-row q16*16+l15. NO barriers: wave-private
// LDS K/V, register fragments as double buffer, explicit waitcnt.
// K-LDS: row s (0..63) x group g (0..7): byte = s*128 + (g^(s&7))*16
// V-LDS: row h (0..63) x group g (0..7): byte = h*128 + (g^(h&7))*16
__global__ __launch_bounds__(64, 2)
void attn(const __bf16* __restrict__ qm, const __bf16* __restrict__ km,
          const __bf16* __restrict__ vT, float* __restrict__ out)
{
    __shared__ __align__(16) char Kb[8192];
    __shared__ __align__(16) char Vb[8192];
    __shared__ __align__(16) __bf16 Ps[16][72];

    const int lane = threadIdx.x;
    const int l15 = lane & 15;
    const int Q = lane >> 4;

    const int batch = blockIdx.x >> 7;
    const int q16 = 127 - (blockIdx.x & 127);   // long strips first per batch
    const int qrow = q16 * 16 + l15;
    const int last = q16 >> 2;

    const __bf16* qb = qm + (size_t)batch * kT * kH;
    const __bf16* kb = km + (size_t)batch * kT * kH;
    const __bf16* vb = vT + (size_t)batch * kH * kT;

    auto stage = [&](int s0) {
        #pragma unroll
        for (int i = 0; i < 8; ++i) {
            const int n = i * 8 + (lane >> 3);
            const int g = (lane & 7) ^ (lane >> 3);
            gl_lds16(&kb[(size_t)(s0 + n) * kH + g * 8], &Kb[i * 1024]);
            gl_lds16(&vb[(size_t)n * kT + s0 + g * 8], &Vb[i * 1024]);
        }
    };

    // Q fragment (B-operand of S^T)
    bf16x8 aq[2];
    aq[0] = *(const bf16x8*)&qb[(size_t)qrow * kH + Q * 8];
    aq[1] = *(const bf16x8*)&qb[(size_t)qrow * kH + 32 + Q * 8];

    f32x4 O[4];
    #pragma unroll
    for (int i = 0; i < 4; ++i) O[i] = (f32x4){0.f, 0.f, 0.f, 0.f};
    float m_ = -3.0e38f, l_ = 0.f;

    stage(0);
    asm volatile("s_waitcnt vmcnt(0)" ::: "memory");

    for (int kt = 0; kt <= last; ++kt) {
        // 1. fragments LDS -> regs (regs are the double buffer)
        bf16x8 kf[8], vf[8];
        #pragma unroll
        for (int ks = 0; ks < 2; ++ks)
            #pragma unroll
            for (int nt = 0; nt < 4; ++nt)
                kf[ks * 4 + nt] = *(const bf16x8*)
                    &Kb[(nt * 16 + l15) * 128 + (((ks * 4 + Q) ^ (l15 & 7)) * 16)];
        #pragma unroll
        for (int ht = 0; ht < 4; ++ht)
            #pragma unroll
            for (int ss = 0; ss < 2; ++ss)
                vf[ht * 2 + ss] = *(const bf16x8*)
                    &Vb[(ht * 16 + l15) * 128 + (((ss * 4 + Q) ^ (l15 & 7)) * 16)];
        asm volatile("s_waitcnt lgkmcnt(0)" ::: "memory");   // reads retired

        // 2. DMA prefetch kt+1 into the same buffers (covered by compute)
        if (kt < last) stage((kt + 1) * 64);

        // 3. S^T = K * Q^T
        f32x4 sacc[4];
        #pragma unroll
        for (int nt = 0; nt < 4; ++nt) sacc[nt] = (f32x4){0.f, 0.f, 0.f, 0.f};
        #pragma unroll
        for (int ks = 0; ks < 2; ++ks)
            #pragma unroll
            for (int nt = 0; nt < 4; ++nt)
                sacc[nt] = MFMA16(kf[ks * 4 + nt], aq[ks], sacc[nt]);

        if (kt == last) {   // diagonal tile mask
            const int s0 = kt * 64;
            #pragma unroll
            for (int nt = 0; nt < 4; ++nt)
                #pragma unroll
                for (int r = 0; r < 4; ++r)
                    if (s0 + nt * 16 + Q * 4 + r > qrow) sacc[nt][r] = -3.0e38f;
        }

        // online softmax: register reduce + 2 shuffles
        float mx = sacc[0][0];
        #pragma unroll
        for (int nt = 0; nt < 4; ++nt)
            #pragma unroll
            for (int r = 0; r < 4; ++r) mx = fmaxf(mx, sacc[nt][r]);
        mx = fmaxf(mx, __shfl_xor(mx, 16));
        mx = fmaxf(mx, __shfl_xor(mx, 32));
        const float mnew = fmaxf(m_, mx);
        const float alpha = __builtin_amdgcn_exp2f(m_ - mnew);
        float rs = 0.f;
        #pragma unroll
        for (int nt = 0; nt < 4; ++nt)
            #pragma unroll
            for (int r = 0; r < 4; ++r) {
                const float pv = __builtin_amdgcn_exp2f(sacc[nt][r] - mnew);
                sacc[nt][r] = pv;
                rs += pv;
            }
        rs += __shfl_xor(rs, 16);
        rs += __shfl_xor(rs, 32);
        l_ = l_ * alpha + rs;
        m_ = mnew;
        #pragma unroll
        for (int ht = 0; ht < 4; ++ht) O[ht] *= alpha;

        // P^T round-trip (wave-private strip; compiler orders via lgkmcnt)
        #pragma unroll
        for (int nt = 0; nt < 4; ++nt) {
            bf16x4 pk;
            #pragma unroll
            for (int r = 0; r < 4; ++r) pk[r] = (__bf16)sacc[nt][r];
            *(bf16x4*)&Ps[l15][nt * 16 + Q * 4] = pk;
        }
        bf16x8 pb0 = *(const bf16x8*)&Ps[l15][Q * 8];
        bf16x8 pb1 = *(const bf16x8*)&Ps[l15][32 + Q * 8];

        // O^T += V^T * P^T
        #pragma unroll
        for (int ht = 0; ht < 4; ++ht) {
            O[ht] = MFMA16(vf[ht * 2 + 0], pb0, O[ht]);
            O[ht] = MFMA16(vf[ht * 2 + 1], pb1, O[ht]);
        }

        // 4. prefetch landed before next iter reads LDS
        asm volatile("s_waitcnt vmcnt(0)" ::: "memory");
    }

    const float inv = 1.0f / l_;
    float* orow = out + ((size_t)batch * kT + qrow) * kH;
    #pragma unroll
    for (int ht = 0; ht < 4; ++ht) {
        float4 o4;
        o4.x = O[ht][0] * inv; o4.y = O[ht][1] * inv;
        o4.z = O[ht][2] * inv; o4.w = O[ht][3] * inv;
        *(float4*)&orow[ht * 16 + Q * 4] = o4;
    }
}

extern "C" void kernel_launch(void* const* d_in, const int* in_sizes, int n_in,
                              void* d_out, int out_size, void* d_ws, size_t ws_size,
                              hipStream_t stream)
{
    (void)in_sizes; (void)n_in; (void)out_size; (void)ws_size;
    const float* x  = (const float*)d_in[0];
    const float* Wk = (const float*)d_in[1];
    const float* Wq = (const float*)d_in[2];
    const float* Wv = (const float*)d_in[3];

    __bf16* WbT  = (__bf16*)d_ws;                     // 384 KiB
    __bf16* qb   = WbT + (size_t)192 * kE;            // 4 MiB each
    __bf16* kbuf = qb + (size_t)kM * kH;
    __bf16* vT   = kbuf + (size_t)kM * kH;

    prep_w<<<48, 256, 0, stream>>>(Wq, Wk, Wv, WbT);
    qkv<<<kM / 64, 256, 0, stream>>>(x, WbT, qb, kbuf, vT);
    attn<<<kB * 128, 64, 0, stream>>>(qb, kbuf, vT, (float*)d_out);
}